// Round 15
// baseline (205.408 us; speedup 1.0000x reference)
//
#include <hip/hip_runtime.h>

#define NF     25                 // input features per row
#define NPAIR  300                // upper-triangle pairs
#define NUNARY 125                // unary outputs per row (5*25)
#define NCOL   425                // output cols per row
#define ROWS   16                 // rows per chunk
#define BLK    256
#define LOADN   (ROWS * NF)               // 400 staged x
#define NVALS   (LOADN + ROWS * NUNARY + 1) // 2401 floats (9.6 KB)
#define ONE_SLOT (LOADN + ROWS * NUNARY)  // vals[2400] == 1.0f
#define TILE_DW (ROWS * NCOL)             // 6800 output dwords per chunk
#define TILE4N  (TILE_DW / 4)             // 1700 float4s
#define C4FULL  (TILE4N / BLK)            // 6 full store passes
#define C4REM   (TILE4N - C4FULL * BLK)   // 164 tail

typedef float f32x4 __attribute__((ext_vector_type(4)));
typedef unsigned int u32;

__global__ __launch_bounds__(BLK, 6) void feat_expand_kernel(
    const float* __restrict__ x, float* __restrict__ out,
    int nrows, int nchunks) {
  // No output tile: out_dword = vals[a] * vals[b], (a,b) static per thread.
  __shared__ float vals[NVALS];             // 9604 B only -> high occupancy

  const int tid = threadIdx.x;

  // Hoisted static descriptors: 7 float4 passes x 4 dwords = 28 u32 in VGPRs
  // (fully unrolled -> compile-time indexed, stays in registers)
  u32 dsc[(C4FULL + 1) * 4];
#pragma unroll
  for (int k = 0; k <= C4FULL; ++k) {
#pragma unroll
    for (int e = 0; e < 4; ++e) {
      int o = 4 * (tid + k * BLK) + e;
      if (o >= TILE_DW) o = 0;              // dummy; predicated off at use
      const int r = o / NCOL, c = o - r * NCOL;
      u32 d;
      if (c < NUNARY) {
        d = (u32)(LOADN + r * NUNARY + c) | ((u32)ONE_SLOT << 16);
      } else {
        int rem = c - NUNARY, i = 0;
        while (rem >= (NF - 1 - i)) { rem -= (NF - 1 - i); ++i; }
        d = (u32)(r * NF + i) | ((u32)(r * NF + i + 1 + rem) << 16);
      }
      dsc[k * 4 + e] = d;
    }
  }

  if (tid == 0) vals[ONE_SLOT] = 1.0f;      // written once, never touched again

  for (long long chunk = blockIdx.x; chunk < nchunks; chunk += gridDim.x) {
    const long long rowbase = chunk * ROWS;
    const long long remr = nrows - rowbase;
    const int rows_here = (int)(remr < ROWS ? remr : ROWS);

    __syncthreads();  // prev chunk's vals readers done (also fences ONE_SLOT)

    // Phase A: load x, publish, compute unary features (400 = 2*256 - 112)
#pragma unroll
    for (int k = 0; k < 2; ++k) {
      const int idx = tid + k * BLK;
      if (idx < LOADN) {
        const int r = idx / NF, i = idx - r * NF;
        float v = 0.0f;
        if (r < rows_here) v = x[rowbase * NF + idx];
        vals[idx] = v;
        float* ur = &vals[LOADN + r * NUNARY];
        const float ax = fabsf(v) + 1e-10f;
        const float l2 = __builtin_amdgcn_logf(ax);      // v_log_f32: log2
        ur[i]          = v;                              // identity
        ur[NF + i]     = v * v;                          // square
        ur[2*NF + i]   = l2 * 0.69314718055994530942f;   // ln = log2*ln2
        ur[3*NF + i]   = sqrtf(ax);                      // v_sqrt_f32
        ur[4*NF + i]   = __builtin_amdgcn_exp2f(l2 * (1.0f/3.0f)); // cbrt
      }
    }
    __syncthreads();  // vals ready

    // Phase C: direct register assembly + nt float4 stores (1700 = 6*256+164)
    // 8 broadcast-heavy LDS reads per float4; LDS reads interleave with
    // VMEM stores in one phase -> continuous store issue, no tile round-trip.
    if (rows_here == ROWS) {
      f32x4* __restrict__ o4 = (f32x4*)(out + rowbase * NCOL);
#pragma unroll
      for (int k = 0; k <= C4FULL; ++k) {
        const int v4 = tid + k * BLK;
        if (k < C4FULL || tid < C4REM) {
          const u32 d0 = dsc[4*k], d1 = dsc[4*k+1], d2 = dsc[4*k+2], d3 = dsc[4*k+3];
          f32x4 ov;
          ov.x = vals[d0 & 0xFFFF] * vals[d0 >> 16];
          ov.y = vals[d1 & 0xFFFF] * vals[d1 >> 16];
          ov.z = vals[d2 & 0xFFFF] * vals[d2 >> 16];
          ov.w = vals[d3 & 0xFFFF] * vals[d3 >> 16];
          __builtin_nontemporal_store(ov, &o4[v4]);
        }
      }
    } else {  // tail chunk (never hit: 524288 % 16 == 0) — inline decode
      const int total = rows_here * NCOL;
      for (int o = tid; o < total; o += BLK) {
        const int r = o / NCOL, c = o - r * NCOL;
        float vv;
        if (c < NUNARY) {
          vv = vals[LOADN + r * NUNARY + c];
        } else {
          int rem2 = c - NUNARY, i = 0;
          while (rem2 >= (NF - 1 - i)) { rem2 -= (NF - 1 - i); ++i; }
          vv = vals[r * NF + i] * vals[r * NF + i + 1 + rem2];
        }
        out[rowbase * NCOL + o] = vv;
      }
    }
  }
}

extern "C" void kernel_launch(void* const* d_in, const int* in_sizes, int n_in,
                              void* d_out, int out_size, void* d_ws, size_t ws_size,
                              hipStream_t stream) {
  const float* x = (const float*)d_in[0];
  float* out = (float*)d_out;

  const int nrows = in_sizes[0] / NF;                 // 524288
  const int nchunks = (nrows + ROWS - 1) / ROWS;      // 32768
  const int grid = nchunks < 4096 ? nchunks : 4096;   // known-good grid

  feat_expand_kernel<<<grid, BLK, 0, stream>>>(x, out, nrows, nchunks);
}

// Round 16
// 190.158 us; speedup vs baseline: 1.0802x; 1.0802x over previous
//
#include <hip/hip_runtime.h>

#define NF    25     // input features per row
#define NPAIR 300    // upper-triangle pairs (25*24/2)
#define NCOL  425    // output cols: 25*5 + 300
#define ROWS  32     // rows per chunk (best point on the chunk-size axis, R14)
#define BLK   512    // 8 waves; 2 blocks/CU residency
#define LOADN  (ROWS * NF)            // 800 staged x per chunk
#define TILE4N (ROWS * NCOL / 4)      // 3400 float4s (54400 B)
#define NP_TOT (ROWS * NPAIR)         // 9600 pair products per chunk
#define KFULL  (NP_TOT / BLK)         // 18 full passes
#define KREM   (NP_TOT - KFULL * BLK) // 384 tail threads
#define C4FULL (TILE4N / BLK)         // 6 full store passes
#define C4REM  (TILE4N - C4FULL * BLK)// 328 tail

typedef float f32x4 __attribute__((ext_vector_type(4)));
typedef unsigned int u32;

__global__ __launch_bounds__(BLK, 4) void feat_expand_kernel(
    const float* __restrict__ x, float* __restrict__ out,
    int nrows, int nchunks) {
  __shared__ f32x4 tile4[TILE4N];           // 54400 B
  __shared__ float xs[LOADN];               // 3200 B  -> 57.6 KB, 2 blocks/CU
  float* tile = (float*)tile4;

  const int tid = threadIdx.x;

  // Hoisted static B2 descriptors (chunk-independent) — R9 technique
  u32 ab[KFULL + 1];
  u32 ti[KFULL + 1];
#pragma unroll
  for (int k = 0; k <= KFULL; ++k) {
    int p = tid + k * BLK;
    if (p >= NP_TOT) p = 0;                 // dummy; predicated off at use
    const int r = p / NPAIR;
    const int q = p - r * NPAIR;
    int rem = q, i = 0;
    while (rem >= (NF - 1 - i)) { rem -= (NF - 1 - i); ++i; }
    ab[k] = (u32)(r * NF + i) | ((u32)(r * NF + i + 1 + rem) << 16);
    ti[k] = (u32)(r * NCOL + 5 * NF + q);
  }

  for (long long chunk = blockIdx.x; chunk < nchunks; chunk += gridDim.x) {
    const long long rowbase = chunk * ROWS;
    const long long remr = nrows - rowbase;
    const int rows_here = (int)(remr < ROWS ? remr : ROWS);

    __syncthreads();  // prev C readers of tile / xs done

    // Phase A: stage 800 x values (2 coalesced passes), keep own 2 in regs
    float va[2];
#pragma unroll
    for (int k = 0; k < 2; ++k) {
      const int idx = tid + k * BLK;        // 800 = 2*512 - 224
      if (idx < LOADN) {
        const int r = idx / NF;
        float v = 0.0f;
        if (r < rows_here) v = x[rowbase * NF + idx];
        xs[idx] = v;
        va[k] = v;
      }
    }
    __syncthreads();  // xs ready

    // Phase B1: unary features from own registers (no xs re-read)
#pragma unroll
    for (int k = 0; k < 2; ++k) {
      const int idx = tid + k * BLK;
      if (idx < LOADN) {
        const int r = idx / NF, i = idx - r * NF;
        float* tr = &tile[r * NCOL];
        const float v  = va[k];
        const float ax = fabsf(v) + 1e-10f;
        const float l2 = __builtin_amdgcn_logf(ax);      // v_log_f32: log2
        tr[i]          = v;                              // identity
        tr[NF + i]     = v * v;                          // square
        tr[2*NF + i]   = l2 * 0.69314718055994530942f;   // ln = log2*ln2
        tr[3*NF + i]   = sqrtf(ax);                      // v_sqrt_f32
        tr[4*NF + i]   = __builtin_amdgcn_exp2f(l2 * (1.0f/3.0f)); // cbrt
      }
    }

    // Phase B2: pair products — static descriptors, zero decode
#pragma unroll
    for (int k = 0; k <= KFULL; ++k) {
      if (k < KFULL || tid < KREM) {
        const u32 d = ab[k];
        tile[ti[k]] = xs[d & 0xFFFF] * xs[d >> 16];
      }
    }
    __syncthreads();  // tile ready

    // Phase C: 54.4 KB contiguous nt float4 burst (3400 = 6*512 + 328)
    if (rows_here == ROWS) {
      f32x4* __restrict__ o4 = (f32x4*)(out + rowbase * NCOL);
#pragma unroll
      for (int k = 0; k <= C4FULL; ++k) {
        const int v4 = tid + k * BLK;
        if (k < C4FULL || tid < C4REM)
          __builtin_nontemporal_store(tile4[v4], &o4[v4]);
      }
    } else {  // tail chunk (not hit when nrows % ROWS == 0)
      const int total = rows_here * NCOL;
      for (int o = tid; o < total; o += BLK)
        out[rowbase * NCOL + o] = tile[o];
    }
  }
}

extern "C" void kernel_launch(void* const* d_in, const int* in_sizes, int n_in,
                              void* d_out, int out_size, void* d_ws, size_t ws_size,
                              hipStream_t stream) {
  const float* x = (const float*)d_in[0];
  float* out = (float*)d_out;

  const int nrows = in_sizes[0] / NF;                 // 524288
  const int nchunks = (nrows + ROWS - 1) / ROWS;      // 16384
  // Exact residency: 2 blocks/CU * 256 CU = 512; each block loops 32 chunks
  // with a warm pipeline and zero block churn (R12 showed churn is costly).
  const int grid = nchunks < 512 ? nchunks : 512;

  feat_expand_kernel<<<grid, BLK, 0, stream>>>(x, out, nrows, nchunks);
}